// Round 1
// baseline (374.270 us; speedup 1.0000x reference)
//
#include <hip/hip_runtime.h>
#include <hip/hip_bf16.h>
#include <math.h>

// Problem constants (fixed by setup_inputs)
#define BB 16
#define TT 8192
#define DD 256
#define MAXSEG 4096   // max possible segments per row (alternating pattern)
#define RPB 16        // segment rows per block in pool_gemm_ln
#define LN_EPS 1e-5f

// ---------------------------------------------------------------------------
// Kernel: transpose W (D x D) so GEMM loads are coalesced along e.
// Wt[d][e] = W[e][d]
__global__ __launch_bounds__(256) void transpose_w(const float* __restrict__ W,
                                                   float* __restrict__ Wt) {
    int d = blockIdx.x;
    int e = threadIdx.x;
    Wt[d * DD + e] = W[e * DD + d];
}

// ---------------------------------------------------------------------------
// Kernel: LayerNorm of b_proj (the output for every empty segment row).
__global__ __launch_bounds__(256) void ln_bias(const float* __restrict__ bp,
                                               const float* __restrict__ gamma,
                                               const float* __restrict__ beta,
                                               float* __restrict__ ln_empty) {
    __shared__ float s1[256];
    __shared__ float s2[256];
    int e = threadIdx.x;
    float v = bp[e];
    s1[e] = v;
    s2[e] = v * v;
    __syncthreads();
    for (int o = 128; o > 0; o >>= 1) {
        if (e < o) { s1[e] += s1[e + o]; s2[e] += s2[e + o]; }
        __syncthreads();
    }
    float mu = s1[0] / (float)DD;
    float var = s2[0] / (float)DD - mu * mu;
    float rs = rsqrtf(fmaxf(var, 0.f) + LN_EPS);
    ln_empty[e] = (v - mu) * rs * gamma[e] + beta[e];
}

// ---------------------------------------------------------------------------
// Kernel: per-row segment scan. One block per batch row.
// Produces seg_start[b][w], counts[b][w] (0 for w>=nseg), nseg[b], and the
// mask output (counts>0 ? 1 : 0).
__global__ __launch_bounds__(256) void seg_scan(const int* __restrict__ ids,
                                                int* __restrict__ counts,
                                                int* __restrict__ seg_start,
                                                int* __restrict__ nseg,
                                                float* __restrict__ mask_out) {
    __shared__ int cnt[TT];       // 32 KB
    __shared__ int wave_tot[4];
    int b = blockIdx.x;
    int tid = threadIdx.x;
    int lane = tid & 63;
    int wv = tid >> 6;
    const int* row = ids + b * TT;

    for (int i = tid; i < TT; i += 256) cnt[i] = 0;
    __syncthreads();

    int base = 0;  // segments seen in earlier chunks (uniform across block)
    for (int c = 0; c < TT; c += 256) {
        int t = c + tid;
        int id = row[t];
        bool nonb = (id != 0);
        bool prevb = (t == 0) || (row[t - 1] == 0);
        bool start = nonb && prevb;

        unsigned long long m = __ballot(start);
        int before = __popcll(m & ((1ull << lane) - 1ull));
        if (lane == 0) wave_tot[wv] = __popcll(m);
        __syncthreads();
        int wbase = 0;
        for (int j = 0; j < wv; ++j) wbase += wave_tot[j];
        int tot = wave_tot[0] + wave_tot[1] + wave_tot[2] + wave_tot[3];

        // inclusive count of starts at positions <= t, minus 1 = segment id
        int seg = base + wbase + before + (start ? 1 : 0) - 1;
        if (start) seg_start[b * TT + seg] = t;
        if (nonb) atomicAdd(&cnt[seg], 1);
        base += tot;
        __syncthreads();
    }

    if (tid == 0) nseg[b] = base;
    for (int i = tid; i < TT; i += 256) {
        int cv = cnt[i];
        counts[b * TT + i] = cv;
        mask_out[b * TT + i] = (cv > 0) ? 1.0f : 0.0f;
    }
}

// ---------------------------------------------------------------------------
// Kernel: write ln_empty into every empty row of the output.
// Grid covers all B*TT rows; 64 rows per block.
__global__ __launch_bounds__(256) void fill_empty(const int* __restrict__ counts,
                                                  const float* __restrict__ ln_empty,
                                                  float* __restrict__ out) {
    int tid = threadIdx.x;
    float v = ln_empty[tid];
    int row0 = blockIdx.x * 64;
    for (int i = 0; i < 64; ++i) {
        int row = row0 + i;
        if (counts[row] == 0) out[row * DD + tid] = v;
    }
}

// ---------------------------------------------------------------------------
// Kernel: fused pool -> GEMM -> LayerNorm for non-empty rows.
// Non-empty rows are exactly w < nseg[b]. RPB rows per block so the 256 KB W
// matrix is re-read ~900/RPB times per batch row instead of ~900.
__global__ __launch_bounds__(256) void pool_gemm_ln(
    const float* __restrict__ x, const float* __restrict__ Wt,
    const float* __restrict__ bp, const float* __restrict__ gamma,
    const float* __restrict__ beta, const int* __restrict__ counts,
    const int* __restrict__ seg_start, const int* __restrict__ nseg,
    float* __restrict__ out) {
    __shared__ float pooled[RPB][DD];   // 16 KB
    __shared__ float outl[RPB][DD];     // 16 KB
    __shared__ float mu_s[RPB];
    __shared__ float rs_s[RPB];

    int b = blockIdx.y;
    int wbase = blockIdx.x * RPB;
    int ns = nseg[b];
    if (wbase >= ns) return;
    int nr = min(RPB, ns - wbase);
    int e = threadIdx.x;

    // ---- pooling: mean of x over each segment's contiguous token range
    for (int r = 0; r < nr; ++r) {
        int w = wbase + r;
        int s = seg_start[b * TT + w];
        int len = counts[b * TT + w];
        const float* xp = x + ((size_t)(b * TT + s)) * DD + e;
        float sum = 0.f;
        for (int t = 0; t < len; ++t) sum += xp[(size_t)t * DD];
        pooled[r][e] = sum / (float)len;
    }
    __syncthreads();

    // ---- GEMM: acc[r] = b_proj[e] + sum_d pooled[r][d] * W[e][d]
    float acc[RPB];
    float bias = bp[e];
#pragma unroll
    for (int r = 0; r < RPB; ++r) acc[r] = bias;

    for (int d0 = 0; d0 < DD; d0 += 4) {
        float w0 = Wt[(d0 + 0) * DD + e];
        float w1 = Wt[(d0 + 1) * DD + e];
        float w2 = Wt[(d0 + 2) * DD + e];
        float w3 = Wt[(d0 + 3) * DD + e];
#pragma unroll
        for (int r = 0; r < RPB; ++r) {
            const float4 p = *(const float4*)&pooled[r][d0];
            acc[r] = fmaf(p.x, w0, acc[r]);
            acc[r] = fmaf(p.y, w1, acc[r]);
            acc[r] = fmaf(p.z, w2, acc[r]);
            acc[r] = fmaf(p.w, w3, acc[r]);
        }
    }

#pragma unroll
    for (int r = 0; r < RPB; ++r) outl[r][e] = acc[r];
    __syncthreads();

    // ---- LN stats: wave wv handles rows wv, wv+4, ...
    int lane = e & 63;
    int wv = e >> 6;
    for (int r = wv; r < nr; r += 4) {
        float s = 0.f, sq = 0.f;
#pragma unroll
        for (int j = 0; j < 4; ++j) {
            float v = outl[r][lane + j * 64];
            s += v;
            sq += v * v;
        }
#pragma unroll
        for (int o = 32; o > 0; o >>= 1) {
            s += __shfl_down(s, o);
            sq += __shfl_down(sq, o);
        }
        if (lane == 0) {
            float mu = s / (float)DD;
            float var = sq / (float)DD - mu * mu;
            mu_s[r] = mu;
            rs_s[r] = rsqrtf(fmaxf(var, 0.f) + LN_EPS);
        }
    }
    __syncthreads();

    // ---- normalize + store (coalesced)
    for (int r = 0; r < nr; ++r) {
        float v = (outl[r][e] - mu_s[r]) * rs_s[r] * gamma[e] + beta[e];
        out[((size_t)(b * TT + wbase + r)) * DD + e] = v;
    }
}

// ---------------------------------------------------------------------------
extern "C" void kernel_launch(void* const* d_in, const int* in_sizes, int n_in,
                              void* d_out, int out_size, void* d_ws, size_t ws_size,
                              hipStream_t stream) {
    const float* x = (const float*)d_in[0];
    const int* ids = (const int*)d_in[1];       // int64 in ref, int32 on device
    const float* W = (const float*)d_in[2];
    const float* bp = (const float*)d_in[3];
    const float* gamma = (const float*)d_in[4];
    const float* beta = (const float*)d_in[5];

    float* out = (float*)d_out;                       // [B, T, D]
    float* mask = out + (size_t)BB * TT * DD;         // [B, T]

    // workspace layout
    char* ws = (char*)d_ws;
    int* counts = (int*)ws;                                    // B*T ints
    int* seg_start = (int*)(ws + (size_t)BB * TT * 4);         // B*T ints
    int* nseg = (int*)(ws + (size_t)2 * BB * TT * 4);          // B ints
    float* Wt = (float*)(ws + (size_t)2 * BB * TT * 4 + 256);  // D*D floats
    float* ln_e = Wt + DD * DD;                                // D floats

    hipLaunchKernelGGL(transpose_w, dim3(DD), dim3(DD), 0, stream, W, Wt);
    hipLaunchKernelGGL(ln_bias, dim3(1), dim3(DD), 0, stream, bp, gamma, beta, ln_e);
    hipLaunchKernelGGL(seg_scan, dim3(BB), dim3(256), 0, stream,
                       ids, counts, seg_start, nseg, mask);
    hipLaunchKernelGGL(fill_empty, dim3(BB * TT / 64), dim3(256), 0, stream,
                       counts, ln_e, out);
    hipLaunchKernelGGL(pool_gemm_ln, dim3(MAXSEG / RPB, BB), dim3(256), 0, stream,
                       x, Wt, bp, gamma, beta, counts, seg_start, nseg, out);
}

// Round 2
// 295.479 us; speedup vs baseline: 1.2667x; 1.2667x over previous
//
#include <hip/hip_runtime.h>
#include <hip/hip_bf16.h>
#include <math.h>

// Problem constants (fixed by setup_inputs)
#define BB 16
#define TT 8192
#define DD 256
#define MAXSEG 4096   // max possible segments per row (alternating pattern)
#define RPB 16        // segment rows per block in pool_gemm_ln
#define LN_EPS 1e-5f

__device__ inline float4 f4add(float4 a, float4 b) {
    a.x += b.x; a.y += b.y; a.z += b.z; a.w += b.w; return a;
}

// ---------------------------------------------------------------------------
// Prelude: transpose W (blocks 0..255) + LayerNorm of b_proj (block 256).
__global__ __launch_bounds__(256) void prelude(const float* __restrict__ W,
                                               const float* __restrict__ bp,
                                               const float* __restrict__ gamma,
                                               const float* __restrict__ beta,
                                               float* __restrict__ Wt,
                                               float* __restrict__ ln_empty) {
    __shared__ float s1[256];
    __shared__ float s2[256];
    int e = threadIdx.x;
    if (blockIdx.x < DD) {
        int d = blockIdx.x;
        Wt[d * DD + e] = W[e * DD + d];
        return;
    }
    float v = bp[e];
    s1[e] = v;
    s2[e] = v * v;
    __syncthreads();
    for (int o = 128; o > 0; o >>= 1) {
        if (e < o) { s1[e] += s1[e + o]; s2[e] += s2[e + o]; }
        __syncthreads();
    }
    float mu = s1[0] / (float)DD;
    float var = s2[0] / (float)DD - mu * mu;
    float rs = rsqrtf(fmaxf(var, 0.f) + LN_EPS);
    ln_empty[e] = (v - mu) * rs * gamma[e] + beta[e];
}

// ---------------------------------------------------------------------------
// Segment scan: one block of 1024 threads per batch row, single pass.
// Segment w count = P[start_{w+1}] - P[start_w] where P = prefix count of
// non-boundary tokens (boundaries between runs contribute 0).
__global__ __launch_bounds__(1024) void seg_scan(const int* __restrict__ ids,
                                                 int* __restrict__ counts,
                                                 int* __restrict__ seg_start,
                                                 int* __restrict__ nseg_g,
                                                 float* __restrict__ mask_out) {
    const int TPT = 8;  // tokens per thread
    __shared__ int wtot_s[16];
    __shared__ int wtot_n[16];
    __shared__ int segs[MAXSEG];
    __shared__ int pvals[MAXSEG];

    int b = blockIdx.x;
    int tid = threadIdx.x;
    int lane = tid & 63;
    int wv = tid >> 6;
    const int* row = ids + b * TT;
    int t0 = tid * TPT;

    int4 q0 = ((const int4*)(row + t0))[0];
    int4 q1 = ((const int4*)(row + t0))[1];
    int v[TPT] = {q0.x, q0.y, q0.z, q0.w, q1.x, q1.y, q1.z, q1.w};
    int prev = (tid == 0) ? 0 : row[t0 - 1];  // 0 == boundary

    bool nb[TPT], st[TPT];
    int cstart = 0, cnon = 0;
#pragma unroll
    for (int j = 0; j < TPT; ++j) {
        nb[j] = (v[j] != 0);
        int pv = (j == 0) ? prev : v[j - 1];
        st[j] = nb[j] && (pv == 0);
        cstart += st[j] ? 1 : 0;
        cnon += nb[j] ? 1 : 0;
    }

    // wave-level inclusive scan of (cstart, cnon)
    int ss = cstart, sn = cnon;
#pragma unroll
    for (int o = 1; o < 64; o <<= 1) {
        int us = __shfl_up(ss, o);
        int un = __shfl_up(sn, o);
        if (lane >= o) { ss += us; sn += un; }
    }
    if (lane == 63) { wtot_s[wv] = ss; wtot_n[wv] = sn; }
    __syncthreads();

    int bs = 0, bn = 0, tot_s = 0, tot_n = 0;
#pragma unroll
    for (int j = 0; j < 16; ++j) {
        int a = wtot_s[j], c = wtot_n[j];
        if (j < wv) { bs += a; bn += c; }
        tot_s += a; tot_n += c;
    }
    bs += ss - cstart;  // exclusive prefix
    bn += sn - cnon;

#pragma unroll
    for (int j = 0; j < TPT; ++j) {
        if (st[j]) { segs[bs] = t0 + j; pvals[bs] = bn; bs++; }
        bn += nb[j] ? 1 : 0;
    }
    __syncthreads();

    int ns = tot_s;
    for (int w = tid; w < TT; w += 1024) {
        int c = 0;
        if (w < ns) {
            int pe = (w + 1 < ns) ? pvals[w + 1] : tot_n;
            c = pe - pvals[w];
            seg_start[b * TT + w] = segs[w];
        }
        counts[b * TT + w] = c;
        mask_out[b * TT + w] = (w < ns) ? 1.0f : 0.0f;
    }
    if (tid == 0) nseg_g[b] = ns;
}

// ---------------------------------------------------------------------------
// Fused pool -> GEMM -> LayerNorm for non-empty rows, ln_empty fill for the
// rest. Grid covers ALL B*T/RPB row-tiles; blocks past nseg just fill.
__global__ __launch_bounds__(256) void pool_gemm_ln(
    const float* __restrict__ x, const float* __restrict__ Wt,
    const float* __restrict__ bp, const float* __restrict__ gamma,
    const float* __restrict__ beta, const int* __restrict__ counts,
    const int* __restrict__ seg_start, const int* __restrict__ nseg,
    const float* __restrict__ ln_e, float* __restrict__ out) {
    __shared__ float pooled[RPB][DD];   // 16 KB, reused for GEMM output
    __shared__ float mu_s[RPB];
    __shared__ float rs_s[RPB];

    int b = blockIdx.y;
    int wbase = blockIdx.x * RPB;
    int ns = nseg[b];
    int e = threadIdx.x;
    int lane = e & 63;
    int wv = e >> 6;

    if (wbase >= ns) {  // pure fill block: every row gets LN(b_proj)
        float v = ln_e[e];
#pragma unroll
        for (int r = 0; r < RPB; ++r)
            out[((size_t)(b * TT + wbase + r)) * DD + e] = v;
        return;
    }
    int nr = min(RPB, ns - wbase);

    // ---- pooling: wave wv owns rows wv, wv+4, wv+8, wv+12; float4 lanes
    for (int r = wv; r < nr; r += 4) {
        int w = wbase + r;
        int s = seg_start[b * TT + w];
        int len = counts[b * TT + w];
        const float4* xp = (const float4*)(x + ((size_t)(b * TT + s)) * DD) + lane;
        float4 a0 = {0, 0, 0, 0}, a1 = a0, a2 = a0, a3 = a0;
        int t = 0;
        for (; t + 4 <= len; t += 4) {
            float4 v0 = xp[(t + 0) * 64];
            float4 v1 = xp[(t + 1) * 64];
            float4 v2 = xp[(t + 2) * 64];
            float4 v3 = xp[(t + 3) * 64];
            a0 = f4add(a0, v0); a1 = f4add(a1, v1);
            a2 = f4add(a2, v2); a3 = f4add(a3, v3);
        }
        for (; t < len; ++t) a0 = f4add(a0, xp[t * 64]);
        a0 = f4add(f4add(a0, a1), f4add(a2, a3));
        float inv = 1.f / (float)len;
        a0.x *= inv; a0.y *= inv; a0.z *= inv; a0.w *= inv;
        *(float4*)&pooled[r][lane * 4] = a0;
    }
    __syncthreads();

    // ---- GEMM: acc[r] = b_proj[e] + sum_d pooled[r][d] * Wt[d][e]
    float acc[RPB];
    float bias = bp[e];
#pragma unroll
    for (int r = 0; r < RPB; ++r) acc[r] = bias;

    for (int d0 = 0; d0 < DD; d0 += 4) {
        float w0 = Wt[(d0 + 0) * DD + e];
        float w1 = Wt[(d0 + 1) * DD + e];
        float w2 = Wt[(d0 + 2) * DD + e];
        float w3 = Wt[(d0 + 3) * DD + e];
#pragma unroll
        for (int r = 0; r < RPB; ++r) {
            const float4 p = *(const float4*)&pooled[r][d0];
            acc[r] = fmaf(p.x, w0, acc[r]);
            acc[r] = fmaf(p.y, w1, acc[r]);
            acc[r] = fmaf(p.z, w2, acc[r]);
            acc[r] = fmaf(p.w, w3, acc[r]);
        }
    }
    __syncthreads();  // done reading pooled; reuse it as output buffer

#pragma unroll
    for (int r = 0; r < RPB; ++r) pooled[r][e] = acc[r];
    __syncthreads();

    // ---- LN stats: wave wv handles rows wv, wv+4, ...
    for (int r = wv; r < nr; r += 4) {
        float s = 0.f, sq = 0.f;
#pragma unroll
        for (int j = 0; j < 4; ++j) {
            float v = pooled[r][lane + j * 64];
            s += v;
            sq += v * v;
        }
#pragma unroll
        for (int o = 32; o > 0; o >>= 1) {
            s += __shfl_down(s, o);
            sq += __shfl_down(sq, o);
        }
        if (lane == 0) {
            float mu = s / (float)DD;
            float var = sq / (float)DD - mu * mu;
            mu_s[r] = mu;
            rs_s[r] = rsqrtf(fmaxf(var, 0.f) + LN_EPS);
        }
    }
    __syncthreads();

    // ---- normalize + store (coalesced); rows >= nr get ln_empty
    float ga = gamma[e], be = beta[e], lev = ln_e[e];
    for (int r = 0; r < RPB; ++r) {
        float v;
        if (r < nr)
            v = (pooled[r][e] - mu_s[r]) * rs_s[r] * ga + be;
        else
            v = lev;
        out[((size_t)(b * TT + wbase + r)) * DD + e] = v;
    }
}

// ---------------------------------------------------------------------------
extern "C" void kernel_launch(void* const* d_in, const int* in_sizes, int n_in,
                              void* d_out, int out_size, void* d_ws, size_t ws_size,
                              hipStream_t stream) {
    const float* x = (const float*)d_in[0];
    const int* ids = (const int*)d_in[1];
    const float* W = (const float*)d_in[2];
    const float* bp = (const float*)d_in[3];
    const float* gamma = (const float*)d_in[4];
    const float* beta = (const float*)d_in[5];

    float* out = (float*)d_out;                       // [B, T, D]
    float* mask = out + (size_t)BB * TT * DD;         // [B, T]

    // workspace layout
    char* ws = (char*)d_ws;
    int* counts = (int*)ws;                                    // B*T ints
    int* seg_start = (int*)(ws + (size_t)BB * TT * 4);         // B*T ints
    int* nseg = (int*)(ws + (size_t)2 * BB * TT * 4);          // B ints
    float* Wt = (float*)(ws + (size_t)2 * BB * TT * 4 + 256);  // D*D floats
    float* ln_e = Wt + DD * DD;                                // D floats

    hipLaunchKernelGGL(prelude, dim3(DD + 1), dim3(DD), 0, stream,
                       W, bp, gamma, beta, Wt, ln_e);
    hipLaunchKernelGGL(seg_scan, dim3(BB), dim3(1024), 0, stream,
                       ids, counts, seg_start, nseg, mask);
    hipLaunchKernelGGL(pool_gemm_ln, dim3(TT / RPB, BB), dim3(256), 0, stream,
                       x, Wt, bp, gamma, beta, counts, seg_start, nseg, ln_e, out);
}

// Round 3
// 285.932 us; speedup vs baseline: 1.3089x; 1.0334x over previous
//
#include <hip/hip_runtime.h>
#include <hip/hip_bf16.h>
#include <math.h>

// Problem constants (fixed by setup_inputs)
#define BB 16
#define TT 8192
#define DD 256
#define MAXSEG 4096   // max possible segments per row (alternating pattern)
#define RPB 16        // segment rows per block in pool_gemm_ln
#define LN_EPS 1e-5f

__device__ inline float4 f4add(float4 a, float4 b) {
    a.x += b.x; a.y += b.y; a.z += b.z; a.w += b.w; return a;
}

// ---------------------------------------------------------------------------
// Prelude: transpose W (blocks 0..255) + LayerNorm of b_proj (block 256).
__global__ __launch_bounds__(256) void prelude(const float* __restrict__ W,
                                               const float* __restrict__ bp,
                                               const float* __restrict__ gamma,
                                               const float* __restrict__ beta,
                                               float* __restrict__ Wt,
                                               float* __restrict__ ln_empty) {
    __shared__ float s1[256];
    __shared__ float s2[256];
    int e = threadIdx.x;
    if (blockIdx.x < DD) {
        int d = blockIdx.x;
        Wt[d * DD + e] = W[e * DD + d];
        return;
    }
    float v = bp[e];
    s1[e] = v;
    s2[e] = v * v;
    __syncthreads();
    for (int o = 128; o > 0; o >>= 1) {
        if (e < o) { s1[e] += s1[e + o]; s2[e] += s2[e + o]; }
        __syncthreads();
    }
    float mu = s1[0] / (float)DD;
    float var = s2[0] / (float)DD - mu * mu;
    float rs = rsqrtf(fmaxf(var, 0.f) + LN_EPS);
    ln_empty[e] = (v - mu) * rs * gamma[e] + beta[e];
}

// ---------------------------------------------------------------------------
// Segment scan: one block of 1024 threads per batch row, single pass.
__global__ __launch_bounds__(1024) void seg_scan(const int* __restrict__ ids,
                                                 int* __restrict__ counts,
                                                 int* __restrict__ seg_start,
                                                 int* __restrict__ nseg_g,
                                                 float* __restrict__ mask_out) {
    const int TPT = 8;  // tokens per thread
    __shared__ int wtot_s[16];
    __shared__ int wtot_n[16];
    __shared__ int segs[MAXSEG];
    __shared__ int pvals[MAXSEG];

    int b = blockIdx.x;
    int tid = threadIdx.x;
    int lane = tid & 63;
    int wv = tid >> 6;
    const int* row = ids + b * TT;
    int t0 = tid * TPT;

    int4 q0 = ((const int4*)(row + t0))[0];
    int4 q1 = ((const int4*)(row + t0))[1];
    int v[TPT] = {q0.x, q0.y, q0.z, q0.w, q1.x, q1.y, q1.z, q1.w};
    int prev = (tid == 0) ? 0 : row[t0 - 1];  // 0 == boundary

    bool nb[TPT], st[TPT];
    int cstart = 0, cnon = 0;
#pragma unroll
    for (int j = 0; j < TPT; ++j) {
        nb[j] = (v[j] != 0);
        int pv = (j == 0) ? prev : v[j - 1];
        st[j] = nb[j] && (pv == 0);
        cstart += st[j] ? 1 : 0;
        cnon += nb[j] ? 1 : 0;
    }

    // wave-level inclusive scan of (cstart, cnon)
    int ss = cstart, sn = cnon;
#pragma unroll
    for (int o = 1; o < 64; o <<= 1) {
        int us = __shfl_up(ss, o);
        int un = __shfl_up(sn, o);
        if (lane >= o) { ss += us; sn += un; }
    }
    if (lane == 63) { wtot_s[wv] = ss; wtot_n[wv] = sn; }
    __syncthreads();

    int bs = 0, bn = 0, tot_s = 0, tot_n = 0;
#pragma unroll
    for (int j = 0; j < 16; ++j) {
        int a = wtot_s[j], c = wtot_n[j];
        if (j < wv) { bs += a; bn += c; }
        tot_s += a; tot_n += c;
    }
    bs += ss - cstart;  // exclusive prefix
    bn += sn - cnon;

#pragma unroll
    for (int j = 0; j < TPT; ++j) {
        if (st[j]) { segs[bs] = t0 + j; pvals[bs] = bn; bs++; }
        bn += nb[j] ? 1 : 0;
    }
    __syncthreads();

    int ns = tot_s;
    for (int w = tid; w < TT; w += 1024) {
        int c = 0;
        if (w < ns) {
            int pe = (w + 1 < ns) ? pvals[w + 1] : tot_n;
            c = pe - pvals[w];
            seg_start[b * TT + w] = segs[w];
        }
        counts[b * TT + w] = c;
        mask_out[b * TT + w] = (w < ns) ? 1.0f : 0.0f;
    }
    if (tid == 0) nseg_g[b] = ns;
}

// ---------------------------------------------------------------------------
// Fused pool -> GEMM -> LayerNorm, barrier-free.
// Wave wv owns rows 4wv..4wv+3 of the 16-row tile. Thread owns output cols
// 4*lane..4*lane+3. Blocks past nseg write LN(b_proj).
// Grid = (batch, tile) so the ~912 work blocks dispatch first, round-robin.
__global__ __launch_bounds__(256) void pool_gemm_ln(
    const float* __restrict__ x, const float* __restrict__ Wt,
    const float* __restrict__ bp, const float* __restrict__ gamma,
    const float* __restrict__ beta, const int* __restrict__ counts,
    const int* __restrict__ seg_start, const int* __restrict__ nseg,
    const float* __restrict__ ln_e, float* __restrict__ out) {
    __shared__ float pooled[RPB][DD];   // 16 KB

    int b = blockIdx.x;
    int wbase = blockIdx.y * RPB;
    int ns = nseg[b];
    int tid = threadIdx.x;
    int lane = tid & 63;
    int wv = tid >> 6;
    int r0 = wv * 4;
    size_t outbase = ((size_t)(b * TT + wbase)) * DD + 4 * lane;

    if (wbase >= ns) {  // pure fill block
        float4 lv = *(const float4*)(ln_e + 4 * lane);
#pragma unroll
        for (int r = 0; r < 4; ++r)
            *(float4*)(out + outbase + (size_t)(r0 + r) * DD) = lv;
        return;
    }
    int nr = min(RPB, ns - wbase);  // rows [0,nr) are real segments

    // ---- pooling: wave-private rows, no barrier needed
#pragma unroll
    for (int r = 0; r < 4; ++r) {
        int row = r0 + r;
        if (row < nr) {
            int w = wbase + row;
            int s = seg_start[b * TT + w];
            int len = counts[b * TT + w];
            const float4* xp = (const float4*)(x + ((size_t)(b * TT + s)) * DD) + lane;
            float4 a0 = {0, 0, 0, 0}, a1 = a0, a2 = a0, a3 = a0;
            int t = 0;
            for (; t + 4 <= len; t += 4) {
                a0 = f4add(a0, xp[(t + 0) * 64]);
                a1 = f4add(a1, xp[(t + 1) * 64]);
                a2 = f4add(a2, xp[(t + 2) * 64]);
                a3 = f4add(a3, xp[(t + 3) * 64]);
            }
            for (; t < len; ++t) a0 = f4add(a0, xp[t * 64]);
            a0 = f4add(f4add(a0, a1), f4add(a2, a3));
            float inv = 1.f / (float)len;
            a0.x *= inv; a0.y *= inv; a0.z *= inv; a0.w *= inv;
            *(float4*)&pooled[row][lane * 4] = a0;
        }
    }

    // ---- GEMM: acc[r][c] = bp[c] + sum_d pooled[r][d] * Wt[d][c]
    float4 acc[4];
    float4 bias4 = *(const float4*)(bp + 4 * lane);
#pragma unroll
    for (int r = 0; r < 4; ++r) acc[r] = bias4;

    if (r0 < nr) {  // wave has at least one real row
        const float4* WtR = (const float4*)Wt;  // [d][64] of float4
#pragma unroll 2
        for (int d0 = 0; d0 < DD; d0 += 4) {
            float4 w0 = WtR[(d0 + 0) * 64 + lane];
            float4 w1 = WtR[(d0 + 1) * 64 + lane];
            float4 w2 = WtR[(d0 + 2) * 64 + lane];
            float4 w3 = WtR[(d0 + 3) * 64 + lane];
#pragma unroll
            for (int r = 0; r < 4; ++r) {
                const float4 p = *(const float4*)&pooled[r0 + r][d0];  // broadcast
                acc[r].x = fmaf(p.x, w0.x, acc[r].x);
                acc[r].y = fmaf(p.x, w0.y, acc[r].y);
                acc[r].z = fmaf(p.x, w0.z, acc[r].z);
                acc[r].w = fmaf(p.x, w0.w, acc[r].w);
                acc[r].x = fmaf(p.y, w1.x, acc[r].x);
                acc[r].y = fmaf(p.y, w1.y, acc[r].y);
                acc[r].z = fmaf(p.y, w1.z, acc[r].z);
                acc[r].w = fmaf(p.y, w1.w, acc[r].w);
                acc[r].x = fmaf(p.z, w2.x, acc[r].x);
                acc[r].y = fmaf(p.z, w2.y, acc[r].y);
                acc[r].z = fmaf(p.z, w2.z, acc[r].z);
                acc[r].w = fmaf(p.z, w2.w, acc[r].w);
                acc[r].x = fmaf(p.w, w3.x, acc[r].x);
                acc[r].y = fmaf(p.w, w3.y, acc[r].y);
                acc[r].z = fmaf(p.w, w3.z, acc[r].z);
                acc[r].w = fmaf(p.w, w3.w, acc[r].w);
            }
        }
    }

    // ---- LN (in-register, per-wave shuffle reduce) + store
    float4 ga4 = *(const float4*)(gamma + 4 * lane);
    float4 be4 = *(const float4*)(beta + 4 * lane);
    float4 lv = *(const float4*)(ln_e + 4 * lane);
#pragma unroll
    for (int r = 0; r < 4; ++r) {
        int row = r0 + r;
        float4 v;
        if (row < nr) {  // wave-uniform branch
            float s = acc[r].x + acc[r].y + acc[r].z + acc[r].w;
            float sq = acc[r].x * acc[r].x + acc[r].y * acc[r].y +
                       acc[r].z * acc[r].z + acc[r].w * acc[r].w;
#pragma unroll
            for (int o = 32; o > 0; o >>= 1) {
                s += __shfl_down(s, o);
                sq += __shfl_down(sq, o);
            }
            s = __shfl(s, 0);
            sq = __shfl(sq, 0);
            float mu = s * (1.f / (float)DD);
            float var = sq * (1.f / (float)DD) - mu * mu;
            float rs = rsqrtf(fmaxf(var, 0.f) + LN_EPS);
            v.x = (acc[r].x - mu) * rs * ga4.x + be4.x;
            v.y = (acc[r].y - mu) * rs * ga4.y + be4.y;
            v.z = (acc[r].z - mu) * rs * ga4.z + be4.z;
            v.w = (acc[r].w - mu) * rs * ga4.w + be4.w;
        } else {
            v = lv;
        }
        *(float4*)(out + outbase + (size_t)row * DD) = v;
    }
}

// ---------------------------------------------------------------------------
extern "C" void kernel_launch(void* const* d_in, const int* in_sizes, int n_in,
                              void* d_out, int out_size, void* d_ws, size_t ws_size,
                              hipStream_t stream) {
    const float* x = (const float*)d_in[0];
    const int* ids = (const int*)d_in[1];
    const float* W = (const float*)d_in[2];
    const float* bp = (const float*)d_in[3];
    const float* gamma = (const float*)d_in[4];
    const float* beta = (const float*)d_in[5];

    float* out = (float*)d_out;                       // [B, T, D]
    float* mask = out + (size_t)BB * TT * DD;         // [B, T]

    // workspace layout
    char* ws = (char*)d_ws;
    int* counts = (int*)ws;                                    // B*T ints
    int* seg_start = (int*)(ws + (size_t)BB * TT * 4);         // B*T ints
    int* nseg = (int*)(ws + (size_t)2 * BB * TT * 4);          // B ints
    float* Wt = (float*)(ws + (size_t)2 * BB * TT * 4 + 256);  // D*D floats
    float* ln_e = Wt + DD * DD;                                // D floats

    hipLaunchKernelGGL(prelude, dim3(DD + 1), dim3(DD), 0, stream,
                       W, bp, gamma, beta, Wt, ln_e);
    hipLaunchKernelGGL(seg_scan, dim3(BB), dim3(1024), 0, stream,
                       ids, counts, seg_start, nseg, mask);
    hipLaunchKernelGGL(pool_gemm_ln, dim3(BB, TT / RPB), dim3(256), 0, stream,
                       x, Wt, bp, gamma, beta, counts, seg_start, nseg, ln_e, out);
}

// Round 4
// 281.308 us; speedup vs baseline: 1.3305x; 1.0164x over previous
//
#include <hip/hip_runtime.h>
#include <hip/hip_bf16.h>
#include <math.h>

// Problem constants (fixed by setup_inputs)
#define BB 16
#define TT 8192
#define DD 256
#define MAXSEG 4096   // max possible segments per row (alternating pattern)
#define RPB 8         // segment rows per block in pool_gemm_ln
#define LN_EPS 1e-5f

__device__ inline float4 f4add(float4 a, float4 b) {
    a.x += b.x; a.y += b.y; a.z += b.z; a.w += b.w; return a;
}

// ---------------------------------------------------------------------------
// Setup kernel (merged): blocks [0,BB) run the per-batch-row segment scan;
// blocks [BB, BB+64) transpose W (4 rows each); block BB+64 computes
// LN(b_proj) with a single wave. 1024 threads each.
__global__ __launch_bounds__(1024) void setup_kernel(
    const int* __restrict__ ids, const float* __restrict__ W,
    const float* __restrict__ bp, const float* __restrict__ gamma,
    const float* __restrict__ beta, int* __restrict__ counts,
    int* __restrict__ seg_start, int* __restrict__ nseg_g,
    float* __restrict__ mask_out, float* __restrict__ Wt,
    float* __restrict__ ln_empty) {
    __shared__ int wtot_s[16];
    __shared__ int wtot_n[16];
    __shared__ int segs[MAXSEG];
    __shared__ int pvals[MAXSEG];

    int tid = threadIdx.x;
    int lane = tid & 63;
    int wv = tid >> 6;

    if (blockIdx.x >= BB) {
        int bi = blockIdx.x - BB;
        if (bi < 64) {  // transpose: 4 d-rows per block
            int d = bi * 4 + (tid >> 8);
            int e = tid & 255;
            Wt[d * DD + e] = W[e * DD + d];
        } else if (wv == 0) {  // LN of b_proj, one wave
            int e0 = lane * 4;
            float4 v = *(const float4*)(bp + e0);
            float s = v.x + v.y + v.z + v.w;
            float sq = v.x * v.x + v.y * v.y + v.z * v.z + v.w * v.w;
#pragma unroll
            for (int o = 32; o > 0; o >>= 1) {
                s += __shfl_down(s, o);
                sq += __shfl_down(sq, o);
            }
            s = __shfl(s, 0);
            sq = __shfl(sq, 0);
            float mu = s * (1.f / (float)DD);
            float var = sq * (1.f / (float)DD) - mu * mu;
            float rs = rsqrtf(fmaxf(var, 0.f) + LN_EPS);
            float4 ge = *(const float4*)(gamma + e0);
            float4 be = *(const float4*)(beta + e0);
            float4 o4;
            o4.x = (v.x - mu) * rs * ge.x + be.x;
            o4.y = (v.y - mu) * rs * ge.y + be.y;
            o4.z = (v.z - mu) * rs * ge.z + be.z;
            o4.w = (v.w - mu) * rs * ge.w + be.w;
            *(float4*)(ln_empty + e0) = o4;
        }
        return;
    }

    // ---- segment scan, one block per batch row
    const int TPT = 8;  // tokens per thread
    int b = blockIdx.x;
    const int* row = ids + b * TT;
    int t0 = tid * TPT;

    int4 q0 = ((const int4*)(row + t0))[0];
    int4 q1 = ((const int4*)(row + t0))[1];
    int v[TPT] = {q0.x, q0.y, q0.z, q0.w, q1.x, q1.y, q1.z, q1.w};
    int prev = (tid == 0) ? 0 : row[t0 - 1];  // 0 == boundary

    bool nb[TPT], st[TPT];
    int cstart = 0, cnon = 0;
#pragma unroll
    for (int j = 0; j < TPT; ++j) {
        nb[j] = (v[j] != 0);
        int pv = (j == 0) ? prev : v[j - 1];
        st[j] = nb[j] && (pv == 0);
        cstart += st[j] ? 1 : 0;
        cnon += nb[j] ? 1 : 0;
    }

    int ss = cstart, sn = cnon;
#pragma unroll
    for (int o = 1; o < 64; o <<= 1) {
        int us = __shfl_up(ss, o);
        int un = __shfl_up(sn, o);
        if (lane >= o) { ss += us; sn += un; }
    }
    if (lane == 63) { wtot_s[wv] = ss; wtot_n[wv] = sn; }
    __syncthreads();

    int bs = 0, bn = 0, tot_s = 0, tot_n = 0;
#pragma unroll
    for (int j = 0; j < 16; ++j) {
        int a = wtot_s[j], c = wtot_n[j];
        if (j < wv) { bs += a; bn += c; }
        tot_s += a; tot_n += c;
    }
    bs += ss - cstart;  // exclusive prefix
    bn += sn - cnon;

#pragma unroll
    for (int j = 0; j < TPT; ++j) {
        if (st[j]) { segs[bs] = t0 + j; pvals[bs] = bn; bs++; }
        bn += nb[j] ? 1 : 0;
    }
    __syncthreads();

    int ns = tot_s;
    for (int w = tid; w < TT; w += 1024) {
        int c = 0;
        if (w < ns) {
            int pe = (w + 1 < ns) ? pvals[w + 1] : tot_n;
            c = pe - pvals[w];
            seg_start[b * TT + w] = segs[w];
        }
        counts[b * TT + w] = c;
        mask_out[b * TT + w] = (w < ns) ? 1.0f : 0.0f;
    }
    if (tid == 0) nseg_g[b] = ns;
}

// ---------------------------------------------------------------------------
// Fused pool -> GEMM -> LayerNorm. 128 threads = 2 waves per block.
// Block owns 8 segment rows. Wave wv pools rows 4wv..4wv+3 (zeros for padding
// rows, which then compute exactly LN(b_proj)). In the GEMM each wave covers
// all 8 rows x 128 cols; thread owns 8 rows x 2 cols (c0, c0+1).
// Wt prefetched one d-quad ahead into registers (hides L2 latency).
__global__ __launch_bounds__(128) void pool_gemm_ln(
    const float* __restrict__ x, const float* __restrict__ Wt,
    const float* __restrict__ bp, const float* __restrict__ gamma,
    const float* __restrict__ beta, const int* __restrict__ counts,
    const int* __restrict__ seg_start, const int* __restrict__ nseg,
    const float* __restrict__ ln_e, float* __restrict__ out) {
    __shared__ float pooled[RPB][DD];   // 8 KB
    __shared__ float red[2][RPB][2];

    int b = blockIdx.x;
    int wbase = blockIdx.y * RPB;
    int ns = nseg[b];
    int tid = threadIdx.x;
    int lane = tid & 63;
    int wv = tid >> 6;
    size_t rowbase = ((size_t)(b * TT + wbase)) * DD;

    if (wbase >= ns) {  // pure fill block: 8 rows of LN(b_proj)
        float4 lv = *(const float4*)(ln_e + 4 * lane);
        float* o = out + rowbase + (size_t)(wv * 4) * DD + 4 * lane;
#pragma unroll
        for (int r = 0; r < 4; ++r)
            *(float4*)(o + (size_t)r * DD) = lv;
        return;
    }
    int nr = min(RPB, ns - wbase);

    // ---- pooling: wave wv owns rows 4wv..4wv+3; padding rows get zeros
#pragma unroll
    for (int r = 0; r < 4; ++r) {
        int row = wv * 4 + r;
        float4 a0 = {0, 0, 0, 0};
        if (row < nr) {
            int w = wbase + row;
            int s = seg_start[b * TT + w];
            int len = counts[b * TT + w];
            const float4* xp = (const float4*)(x + ((size_t)(b * TT + s)) * DD) + lane;
            float4 a1 = a0, a2 = a0, a3 = a0;
            int t = 0;
            for (; t + 4 <= len; t += 4) {
                a0 = f4add(a0, xp[(t + 0) * 64]);
                a1 = f4add(a1, xp[(t + 1) * 64]);
                a2 = f4add(a2, xp[(t + 2) * 64]);
                a3 = f4add(a3, xp[(t + 3) * 64]);
            }
            for (; t < len; ++t) a0 = f4add(a0, xp[t * 64]);
            a0 = f4add(f4add(a0, a1), f4add(a2, a3));
            float inv = 1.f / (float)len;
            a0.x *= inv; a0.y *= inv; a0.z *= inv; a0.w *= inv;
        }
        *(float4*)&pooled[row][lane * 4] = a0;
    }
    __syncthreads();

    // ---- GEMM with register prefetch of Wt (one d-quad ahead)
    int c0 = wv * 128 + lane * 2;
    float2 acc[RPB];
    float2 bias2 = *(const float2*)(bp + c0);
#pragma unroll
    for (int r = 0; r < RPB; ++r) acc[r] = bias2;

    const float* Wc = Wt + c0;
    float2 w0 = *(const float2*)(Wc + 0 * DD);
    float2 w1 = *(const float2*)(Wc + 1 * DD);
    float2 w2 = *(const float2*)(Wc + 2 * DD);
    float2 w3 = *(const float2*)(Wc + 3 * DD);
#pragma unroll 1
    for (int d0 = 0; d0 < DD; d0 += 4) {
        int dn = (d0 + 4) & 255;  // wraps harmlessly on the last iteration
        float2 n0 = *(const float2*)(Wc + (dn + 0) * DD);
        float2 n1 = *(const float2*)(Wc + (dn + 1) * DD);
        float2 n2 = *(const float2*)(Wc + (dn + 2) * DD);
        float2 n3 = *(const float2*)(Wc + (dn + 3) * DD);
#pragma unroll
        for (int r = 0; r < RPB; ++r) {
            const float4 p = *(const float4*)&pooled[r][d0];  // wave-uniform broadcast
            acc[r].x = fmaf(p.x, w0.x, acc[r].x);
            acc[r].y = fmaf(p.x, w0.y, acc[r].y);
            acc[r].x = fmaf(p.y, w1.x, acc[r].x);
            acc[r].y = fmaf(p.y, w1.y, acc[r].y);
            acc[r].x = fmaf(p.z, w2.x, acc[r].x);
            acc[r].y = fmaf(p.z, w2.y, acc[r].y);
            acc[r].x = fmaf(p.w, w3.x, acc[r].x);
            acc[r].y = fmaf(p.w, w3.y, acc[r].y);
        }
        w0 = n0; w1 = n1; w2 = n2; w3 = n3;
    }

    // ---- LN: wave-partial sums over 128 cols, combine across waves via LDS.
    // Padding rows (pooled == 0) give acc == bias -> LN(b_proj) exactly.
#pragma unroll
    for (int r = 0; r < RPB; ++r) {
        float s = acc[r].x + acc[r].y;
        float sq = acc[r].x * acc[r].x + acc[r].y * acc[r].y;
#pragma unroll
        for (int o = 32; o > 0; o >>= 1) {
            s += __shfl_down(s, o);
            sq += __shfl_down(sq, o);
        }
        if (lane == 0) { red[wv][r][0] = s; red[wv][r][1] = sq; }
    }
    __syncthreads();

    float ga0 = gamma[c0], ga1 = gamma[c0 + 1];
    float be0 = beta[c0], be1 = beta[c0 + 1];
#pragma unroll
    for (int r = 0; r < RPB; ++r) {
        float s = red[0][r][0] + red[1][r][0];
        float sq = red[0][r][1] + red[1][r][1];
        float mu = s * (1.f / (float)DD);
        float var = sq * (1.f / (float)DD) - mu * mu;
        float rs = rsqrtf(fmaxf(var, 0.f) + LN_EPS);
        float2 v;
        v.x = (acc[r].x - mu) * rs * ga0 + be0;
        v.y = (acc[r].y - mu) * rs * ga1 + be1;
        *(float2*)(out + rowbase + (size_t)r * DD + c0) = v;
    }
}

// ---------------------------------------------------------------------------
extern "C" void kernel_launch(void* const* d_in, const int* in_sizes, int n_in,
                              void* d_out, int out_size, void* d_ws, size_t ws_size,
                              hipStream_t stream) {
    const float* x = (const float*)d_in[0];
    const int* ids = (const int*)d_in[1];
    const float* W = (const float*)d_in[2];
    const float* bp = (const float*)d_in[3];
    const float* gamma = (const float*)d_in[4];
    const float* beta = (const float*)d_in[5];

    float* out = (float*)d_out;                       // [B, T, D]
    float* mask = out + (size_t)BB * TT * DD;         // [B, T]

    // workspace layout
    char* ws = (char*)d_ws;
    int* counts = (int*)ws;                                    // B*T ints
    int* seg_start = (int*)(ws + (size_t)BB * TT * 4);         // B*T ints
    int* nseg = (int*)(ws + (size_t)2 * BB * TT * 4);          // B ints
    float* Wt = (float*)(ws + (size_t)2 * BB * TT * 4 + 256);  // D*D floats
    float* ln_e = Wt + DD * DD;                                // D floats

    hipLaunchKernelGGL(setup_kernel, dim3(BB + 64 + 1), dim3(1024), 0, stream,
                       ids, W, bp, gamma, beta, counts, seg_start, nseg, mask,
                       Wt, ln_e);
    hipLaunchKernelGGL(pool_gemm_ln, dim3(BB, TT / RPB), dim3(128), 0, stream,
                       x, Wt, bp, gamma, beta, counts, seg_start, nseg, ln_e, out);
}